// Round 4
// baseline (436.784 us; speedup 1.0000x reference)
//
#include <hip/hip_runtime.h>
#include <stdint.h>

typedef __bf16 bf16x8 __attribute__((ext_vector_type(8)));
typedef float  f32x4  __attribute__((ext_vector_type(4)));
typedef unsigned short u16x8 __attribute__((ext_vector_type(8)));

__device__ __forceinline__ unsigned short f2bf(float f) {
    union { float f; unsigned int u; } v; v.f = f;
    unsigned int u = v.u;
    return (unsigned short)((u + 0x7FFFu + ((u >> 16) & 1u)) >> 16);
}

// ---------------------------------------------------------------------------
// Kernel 1: cast x (fp32) -> bf16 A[M][K]. 8 elems/thread, 16B stores.
// ---------------------------------------------------------------------------
__global__ void cast_x_kernel(const float4* __restrict__ X,
                              u16x8* __restrict__ A, int n8) {
    int i = blockIdx.x * blockDim.x + threadIdx.x;
    if (i < n8) {
        float4 v0 = X[i * 2];
        float4 v1 = X[i * 2 + 1];
        u16x8 o;
        o[0] = f2bf(v0.x); o[1] = f2bf(v0.y); o[2] = f2bf(v0.z); o[3] = f2bf(v0.w);
        o[4] = f2bf(v1.x); o[5] = f2bf(v1.y); o[6] = f2bf(v1.z); o[7] = f2bf(v1.w);
        A[i] = o;
    }
}

// ---------------------------------------------------------------------------
// Kernel 2: FWHT each row of W (len 2048), scale 1/sqrt(2048), emit bf16.
// H symmetric+orthogonal: (xH/vn) W^T == x (W H/vn)^T.
// ---------------------------------------------------------------------------
__global__ void fwht_w_kernel(const float* __restrict__ W,
                              unsigned short* __restrict__ Bt) {
    const int n = 2048;
    __shared__ float buf[2048];
    const float* src = W + (size_t)blockIdx.x * n;
    for (int i = threadIdx.x; i < n; i += 256) buf[i] = src[i];
    __syncthreads();
    for (int len = 1; len < n; len <<= 1) {
        for (int j = threadIdx.x; j < n / 2; j += 256) {
            int idx = ((j & ~(len - 1)) << 1) | (j & (len - 1));
            float a = buf[idx], b = buf[idx + len];
            buf[idx]       = a + b;
            buf[idx + len] = a - b;
        }
        __syncthreads();
    }
    const float scale = 0.02209708691207961f; // 1/sqrt(2048)
    unsigned short* dst = Bt + (size_t)blockIdx.x * n;
    for (int i = threadIdx.x; i < n; i += 256) dst[i] = f2bf(buf[i] * scale);
}

// ---------------------------------------------------------------------------
// Kernel 3 (R7): C[M][N] = A[M][K]*B[N][K]^T + bias, bf16 MFMA 16x16x32.
//
// R6 post-mortem: latency-convoy-bound at 2 waves/SIMD; LDS pipe (96
// ds_read_b128 + 32KB stage-writes per tile per CU) >= MFMA need. R7 cuts
// the LDS floor below the MFMA floor: B (8 MB, L2-resident) bypasses LDS
// entirely — B-frags are loaded global->VGPR (compiler-tracked RAW),
// double-buffered one tile ahead. LDS now holds A only: 4-slab ring of
// 256x32 (64 KiB). Per-tile LDS: 64 ds_read_b128 + 16 KB writes (~900 cyc)
// < MFMA 1030 cyc. A-staging keeps the counted-vmcnt ledger (depth-2):
//   tile t: issue B(t+1)[4 loads], STAGE_A(t+2)[2], vmcnt(6) confirms
//   {B(t), A(t+1)}, MFMA, barrier publishes slab t+1. Tail: vmcnt(4)@NT-2,
//   vmcnt(0)@NT-1. Fences pin VMEM issue order so the ledger counts hold.
// XCD swizzle (bijective, 512%8==0): each XCD owns ONE 256-col n-panel ->
// its B slice is 1 MB (fits 4 MB per-XCD L2); A served from L3 (64 MB).
// ---------------------------------------------------------------------------
constexpr int GK = 2048;       // K (fixed by problem)
constexpr int GN = 2048;       // N
constexpr int NT = GK / 32;    // 64 k-tiles

__global__ __launch_bounds__(512) void had_gemm_kernel(
    const unsigned short* __restrict__ A,   // [M][K] bf16
    const unsigned short* __restrict__ B,   // [N][K] bf16 (W')
    const float* __restrict__ bias,         // [N]
    float* __restrict__ C)                  // [M][N] fp32
{
    // A-only LDS: 4 slabs x 256 rows x 32 k x 2B = 64 KiB
    __shared__ __attribute__((aligned(16))) unsigned short As[4][256 * 32];

    const int tid  = threadIdx.x;
    const int lane = tid & 63;
    const int wave = tid >> 6;      // 0..7
    const int wm   = wave & 1;      // row half  (128 rows)
    const int wn   = wave >> 1;     // col quarter (64 cols)
    const int l16  = lane & 15;
    const int quad = lane >> 4;

    // XCD-aware bijective remap: XCD k (= lin%8) owns n-panel bx=k.
    const int lin = blockIdx.x + blockIdx.y * 8;       // 0..511
    const int w   = (lin & 7) * 64 + (lin >> 3);
    const int n0  = (w >> 6) * 256;
    const int m0  = (w & 63) * 256;

    f32x4 acc[8][4] = {};

    // ---- A staging: thread -> row = i*128 + tid/4, 16B chunk (tid&3).
    // Source col pre-swizzled; LDS dest linear (wave base + lane*16).
    const int srow = tid >> 2;
    const int swzc = ((tid & 3) * 16) ^ (((srow >> 1) & 3) << 4);
    const char* gA0 = (const char*)(A + (size_t)(m0 + srow) * GK) + swzc;
    const char* gA1 = (const char*)(A + (size_t)(m0 + 128 + srow) * GK) + swzc;
    // ((srow+128)>>1)&3 == (srow>>1)&3, so swzc valid for both halves.

#define STAGE_A(t_) { const int sl_ = (t_) & 3;                                   \
    __builtin_amdgcn_global_load_lds(                                             \
        (const __attribute__((address_space(1))) void*)(gA0 + (t_) * 64),         \
        (__attribute__((address_space(3))) void*)(&As[sl_][wave * 512]), 16, 0, 0);\
    __builtin_amdgcn_global_load_lds(                                             \
        (const __attribute__((address_space(1))) void*)(gA1 + (t_) * 64),         \
        (__attribute__((address_space(3))) void*)(&As[sl_][4096 + wave * 512]), 16, 0, 0); }

    // ---- B frags straight from global (L2). lane: row = n0+wn*64+j*16+l16,
    // k = t*32 + quad*8 .. +8. 16B/lane -> global_load_dwordx4.
    const unsigned short* gBF = B + (size_t)(n0 + wn * 64 + l16) * GK + quad * 8;
#define LOADB(dst_, t_) {                                                         \
    const unsigned short* p_ = gBF + (size_t)(t_) * 32;                           \
    dst_[0] = *(const bf16x8*)(p_);                                               \
    dst_[1] = *(const bf16x8*)(p_ + 16 * GK);                                     \
    dst_[2] = *(const bf16x8*)(p_ + 32 * GK);                                     \
    dst_[3] = *(const bf16x8*)(p_ + 48 * GK); }

    // ---- A fragment read offsets (same XOR as staging source) ----
    const int arow = wm * 128 + l16;
    const int sw   = ((l16 >> 1) & 3) << 4;
    const unsigned aoff = (unsigned)(arow * 64 + quad * 16) ^ sw;
    const char* sabase = (const char*)&As[0][0];

    bf16x8 bfrA[4], bfrB[4];

    // ---- prologue: B(0), A(0), A(1); confirm B(0)+A(0); publish slab 0 ----
    LOADB(bfrA, 0)
    asm volatile("" ::: "memory");
    STAGE_A(0) STAGE_A(1)
    asm volatile("s_waitcnt vmcnt(2)" ::: "memory");   // B0 + A0 done (A1 may fly)
    __builtin_amdgcn_s_barrier();
    asm volatile("" ::: "memory");

    // ---- main loop: pair-unrolled for static bfr double-buffer indexing ----
#define TILE_BODY(t_, CUR_, NXT_) {                                               \
    const char* sa = sabase + (size_t)((t_) & 3) * 16384;                         \
    bf16x8 af[8];                                                                 \
    if ((t_) + 1 < NT) { LOADB(NXT_, (t_) + 1) }                                  \
    asm volatile("" ::: "memory");                                                \
    if ((t_) + 2 < NT) STAGE_A((t_) + 2);                                         \
    _Pragma("unroll")                                                             \
    for (int i = 0; i < 4; ++i)                                                   \
        af[i] = *(const bf16x8*)(sa + (aoff + i * 1024u));                        \
    if ((t_) < NT - 2)       { asm volatile("s_waitcnt vmcnt(6)" ::: "memory"); } \
    else if ((t_) == NT - 2) { asm volatile("s_waitcnt vmcnt(4)" ::: "memory"); } \
    else                     { asm volatile("s_waitcnt vmcnt(0)" ::: "memory"); } \
    __builtin_amdgcn_s_setprio(1);                                                \
    _Pragma("unroll")                                                             \
    for (int i = 0; i < 4; ++i)                                                   \
        _Pragma("unroll")                                                         \
        for (int j = 0; j < 4; ++j)                                               \
            acc[i][j] = __builtin_amdgcn_mfma_f32_16x16x32_bf16(                  \
                af[i], CUR_[j], acc[i][j], 0, 0, 0);                              \
    __builtin_amdgcn_s_setprio(0);                                                \
    _Pragma("unroll")                                                             \
    for (int i = 0; i < 4; ++i)                                                   \
        af[4 + i] = *(const bf16x8*)(sa + (aoff + (4 + i) * 1024u));              \
    __builtin_amdgcn_s_setprio(1);                                                \
    _Pragma("unroll")                                                             \
    for (int i = 0; i < 4; ++i)                                                   \
        _Pragma("unroll")                                                         \
        for (int j = 0; j < 4; ++j)                                               \
            acc[4 + i][j] = __builtin_amdgcn_mfma_f32_16x16x32_bf16(              \
                af[4 + i], CUR_[j], acc[4 + i][j], 0, 0, 0);                      \
    __builtin_amdgcn_s_setprio(0);                                                \
    asm volatile("" ::: "memory");                                                \
    __builtin_amdgcn_s_barrier();                                                 \
    asm volatile("" ::: "memory"); }

    for (int t = 0; t < NT; t += 2) {
        TILE_BODY(t,     bfrA, bfrB)
        TILE_BODY(t + 1, bfrB, bfrA)
    }
#undef TILE_BODY
#undef STAGE_A
#undef LOADB

    // ---- epilogue: C/D layout col=lane&15, row=quad*4+reg (m89-verified) ----
    float bv[4];
    #pragma unroll
    for (int j = 0; j < 4; ++j) bv[j] = bias[n0 + wn * 64 + j * 16 + l16];

    #pragma unroll
    for (int i = 0; i < 8; ++i) {
        #pragma unroll
        for (int r = 0; r < 4; ++r) {
            int row = m0 + wm * 128 + i * 16 + quad * 4 + r;
            float* cp = C + (size_t)row * GN + (n0 + wn * 64 + l16);
            #pragma unroll
            for (int j = 0; j < 4; ++j)
                cp[j * 16] = acc[i][j][r] + bv[j];
        }
    }
}

// ---------------------------------------------------------------------------
extern "C" void kernel_launch(void* const* d_in, const int* in_sizes, int n_in,
                              void* d_out, int out_size, void* d_ws, size_t ws_size,
                              hipStream_t stream) {
    const float* x = (const float*)d_in[0];  // [4,4096,2048] fp32
    const float* W = (const float*)d_in[1];  // [2048,2048]  fp32
    const float* b = (const float*)d_in[2];  // [2048]       fp32
    float* out = (float*)d_out;              // [4,4096,2048] fp32

    const int d = in_sizes[2];          // 2048
    const int M = in_sizes[0] / d;      // 16384
    const int N = d, K = d;

    // Workspace: A bf16 [M][K] (64 MB) + W' bf16 [N][K] (8 MB)
    unsigned short* A_ws  = (unsigned short*)d_ws;
    unsigned short* Bt_ws = A_ws + (size_t)M * K;

    int n8 = in_sizes[0] / 8;
    cast_x_kernel<<<(n8 + 255) / 256, 256, 0, stream>>>(
        (const float4*)x, (u16x8*)A_ws, n8);

    fwht_w_kernel<<<N, 256, 0, stream>>>(W, Bt_ws);

    dim3 grid(N / 256, M / 256);  // (8, 64) = 512 blocks
    had_gemm_kernel<<<grid, 512, 0, stream>>>(A_ws, Bt_ws, b, out);
}

// Round 5
// 374.659 us; speedup vs baseline: 1.1658x; 1.1658x over previous
//
#include <hip/hip_runtime.h>
#include <stdint.h>

typedef __bf16 bf16x8 __attribute__((ext_vector_type(8)));
typedef float  f32x4  __attribute__((ext_vector_type(4)));
typedef unsigned short u16x8 __attribute__((ext_vector_type(8)));

__device__ __forceinline__ unsigned short f2bf(float f) {
    union { float f; unsigned int u; } v; v.f = f;
    unsigned int u = v.u;
    return (unsigned short)((u + 0x7FFFu + ((u >> 16) & 1u)) >> 16);
}

// ---------------------------------------------------------------------------
// Kernel 1: cast x (fp32) -> bf16 A[M][K]. 8 elems/thread, 16B stores.
// ---------------------------------------------------------------------------
__global__ void cast_x_kernel(const float4* __restrict__ X,
                              u16x8* __restrict__ A, int n8) {
    int i = blockIdx.x * blockDim.x + threadIdx.x;
    if (i < n8) {
        float4 v0 = X[i * 2];
        float4 v1 = X[i * 2 + 1];
        u16x8 o;
        o[0] = f2bf(v0.x); o[1] = f2bf(v0.y); o[2] = f2bf(v0.z); o[3] = f2bf(v0.w);
        o[4] = f2bf(v1.x); o[5] = f2bf(v1.y); o[6] = f2bf(v1.z); o[7] = f2bf(v1.w);
        A[i] = o;
    }
}

// ---------------------------------------------------------------------------
// Kernel 2: FWHT each row of W (len 2048), scale 1/sqrt(2048), emit bf16.
// H symmetric+orthogonal: (xH/vn) W^T == x (W H/vn)^T.
// ---------------------------------------------------------------------------
__global__ void fwht_w_kernel(const float* __restrict__ W,
                              unsigned short* __restrict__ Bt) {
    const int n = 2048;
    __shared__ float buf[2048];
    const float* src = W + (size_t)blockIdx.x * n;
    for (int i = threadIdx.x; i < n; i += 256) buf[i] = src[i];
    __syncthreads();
    for (int len = 1; len < n; len <<= 1) {
        for (int j = threadIdx.x; j < n / 2; j += 256) {
            int idx = ((j & ~(len - 1)) << 1) | (j & (len - 1));
            float a = buf[idx], b = buf[idx + len];
            buf[idx]       = a + b;
            buf[idx + len] = a - b;
        }
        __syncthreads();
    }
    const float scale = 0.02209708691207961f; // 1/sqrt(2048)
    unsigned short* dst = Bt + (size_t)blockIdx.x * n;
    for (int i = threadIdx.x; i < n; i += 256) dst[i] = f2bf(buf[i] * scale);
}

// ---------------------------------------------------------------------------
// Kernel 3 (R8 = R6 + derived-waits): C = A*B^T + bias, bf16 MFMA 16x16x32.
//
// Theory (R5/R6/R7 post-mortem): plain-C++ ds_reads of As/Bs force LLVM's
// waitcnt pass to insert s_waitcnt vmcnt(0) before each read batch (it
// can't prove the in-flight global_load_lds DMAs to slab (t+3)&3 don't
// alias reads from slab t&3) -> the counted-vmcnt pipeline silently became
// the "drain0" variant (m218: -38..-73%). Fix: ds_read_b128 via inline asm
// (invisible to alias analysis) + manual s_waitcnt lgkmcnt(0) +
// sched_barrier(0) after each read cluster (rule 18). Everything else
// (staging, XOR swizzle verified 0-conflict, 4-slab ring, depth-3 ledger
// vmcnt(8)/4/0, setprio, 1 barrier/tile) is identical to R6.
//
// Ledger: tile t issues 4 loads (->t+3) at top; at tile end vmcnt(8)
// leaves exactly {->t+2, ->t+3} in flight and confirms ->t+1; barrier
// publishes slab t+1. WAR: slab (t+3)&3 == (t-1)&3 was last read in tile
// t-1; those reads completed at t-1's lgkmcnt(0), before its tile-end
// barrier, which precedes this stage issue.
// ---------------------------------------------------------------------------
constexpr int GK = 2048;       // K (fixed by problem)
constexpr int GN = 2048;       // N
constexpr int NT = GK / 32;    // 64 k-tiles

__device__ __forceinline__ bf16x8 ds_read_b128_asm(unsigned addr) {
    bf16x8 r;
    asm volatile("ds_read_b128 %0, %1" : "=v"(r) : "v"(addr));
    return r;
}

__global__ __launch_bounds__(512, 2) void had_gemm_kernel(
    const unsigned short* __restrict__ A,   // [M][K] bf16
    const unsigned short* __restrict__ B,   // [N][K] bf16 (W')
    const float* __restrict__ bias,         // [N]
    float* __restrict__ C)                  // [M][N] fp32
{
    __shared__ __attribute__((aligned(16))) unsigned short As[4][256 * 32];
    __shared__ __attribute__((aligned(16))) unsigned short Bs[4][256 * 32];

    const int tid  = threadIdx.x;
    const int lane = tid & 63;
    const int wave = tid >> 6;      // 0..7
    const int wm   = wave & 1;      // row half  (128 rows)
    const int wn   = wave >> 1;     // col quarter (64 cols)
    const int l16  = lane & 15;
    const int quad = lane >> 4;
    const int m0 = blockIdx.y * 256;
    const int n0 = blockIdx.x * 256;

    f32x4 acc[8][4] = {};

    // ---- staging geometry (R6-verified): thread -> row = i*128 + tid/4,
    // 16B chunk (tid&3). Source col pre-swizzled; LDS dest linear.
    const int srow = tid >> 2;
    const int swzc = ((tid & 3) * 16) ^ (((srow >> 1) & 3) << 4);
    const char* gA0 = (const char*)(A + (size_t)(m0 + srow) * GK) + swzc;
    const char* gA1 = (const char*)(A + (size_t)(m0 + 128 + srow) * GK) + swzc;
    const char* gB0 = (const char*)(B + (size_t)(n0 + srow) * GK) + swzc;
    const char* gB1 = (const char*)(B + (size_t)(n0 + 128 + srow) * GK) + swzc;

#define STAGE_A(t_) { const int sl_ = (t_) & 3;                                   \
    __builtin_amdgcn_global_load_lds(                                             \
        (const __attribute__((address_space(1))) void*)(gA0 + (t_) * 64),         \
        (__attribute__((address_space(3))) void*)(&As[sl_][wave * 512]), 16, 0, 0);\
    __builtin_amdgcn_global_load_lds(                                             \
        (const __attribute__((address_space(1))) void*)(gA1 + (t_) * 64),         \
        (__attribute__((address_space(3))) void*)(&As[sl_][4096 + wave * 512]), 16, 0, 0); }
#define STAGE_B(t_) { const int sl_ = (t_) & 3;                                   \
    __builtin_amdgcn_global_load_lds(                                             \
        (const __attribute__((address_space(1))) void*)(gB0 + (t_) * 64),         \
        (__attribute__((address_space(3))) void*)(&Bs[sl_][wave * 512]), 16, 0, 0);\
    __builtin_amdgcn_global_load_lds(                                             \
        (const __attribute__((address_space(1))) void*)(gB1 + (t_) * 64),         \
        (__attribute__((address_space(3))) void*)(&Bs[sl_][4096 + wave * 512]), 16, 0, 0); }

    // ---- fragment read offsets (same XOR as staging source; 0-conflict
    // verified on HW in R5/R6/R7) ----
    const int arow = wm * 128 + l16;
    const int brow = wn * 64 + l16;
    const int sw   = ((l16 >> 1) & 3) << 4;   // row bits 1-2 come from l16
    const unsigned aoff = (unsigned)(arow * 64 + quad * 16) ^ sw;
    const unsigned boff = (unsigned)(brow * 64 + quad * 16) ^ sw;
    // LDS byte bases as 32-bit addresses for asm ds_read
    const unsigned asBase = (unsigned)(uintptr_t)
        (__attribute__((address_space(3))) void*)&As[0][0];
    const unsigned bsBase = (unsigned)(uintptr_t)
        (__attribute__((address_space(3))) void*)&Bs[0][0];

    // ---- prologue: stage tiles 0..2 (12 loads), confirm tile 0 ----
    STAGE_A(0) STAGE_B(0) asm volatile("" ::: "memory");
    STAGE_A(1) STAGE_B(1) asm volatile("" ::: "memory");
    STAGE_A(2) STAGE_B(2)
    asm volatile("s_waitcnt vmcnt(8)" ::: "memory");   // oldest 4 = tile 0 done
    __builtin_amdgcn_s_barrier();
    asm volatile("" ::: "memory");

    for (int t = 0; t < NT; ++t) {
        const unsigned sa = asBase + (unsigned)(t & 3) * 16384u;
        const unsigned sb = bsBase + (unsigned)(t & 3) * 16384u;
        bf16x8 af[8], bfr[4];

        // stage tile t+3 first: DMA queue fills under this tile's compute
        if (t + 3 < NT) { STAGE_A(t + 3) STAGE_B(t + 3) }
        asm volatile("" ::: "memory");   // pin DMA issue above the waits below

        // ---- cluster 1 reads (asm: invisible to alias analysis) ----
        #pragma unroll
        for (int j = 0; j < 4; ++j)
            bfr[j] = ds_read_b128_asm(sb + boff + j * 1024u);
        #pragma unroll
        for (int i = 0; i < 4; ++i)
            af[i] = ds_read_b128_asm(sa + aoff + i * 1024u);
        asm volatile("s_waitcnt lgkmcnt(0)" ::: "memory");
        __builtin_amdgcn_sched_barrier(0);   // rule 18: MFMA must not hoist

        __builtin_amdgcn_s_setprio(1);
        #pragma unroll
        for (int i = 0; i < 4; ++i)
            #pragma unroll
            for (int j = 0; j < 4; ++j)
                acc[i][j] = __builtin_amdgcn_mfma_f32_16x16x32_bf16(
                    af[i], bfr[j], acc[i][j], 0, 0, 0);
        __builtin_amdgcn_s_setprio(0);

        // ---- cluster 2 reads ----
        #pragma unroll
        for (int i = 0; i < 4; ++i)
            af[4 + i] = ds_read_b128_asm(sa + aoff + (4 + i) * 1024u);
        asm volatile("s_waitcnt lgkmcnt(0)" ::: "memory");
        __builtin_amdgcn_sched_barrier(0);

        __builtin_amdgcn_s_setprio(1);
        #pragma unroll
        for (int i = 0; i < 4; ++i)
            #pragma unroll
            for (int j = 0; j < 4; ++j)
                acc[4 + i][j] = __builtin_amdgcn_mfma_f32_16x16x32_bf16(
                    af[4 + i], bfr[j], acc[4 + i][j], 0, 0, 0);
        __builtin_amdgcn_s_setprio(0);

        // tile end: counted wait (tile t+1 confirmed; t+2/t+3 stay in flight)
        if (t < NT - 3)       { asm volatile("s_waitcnt vmcnt(8)" ::: "memory"); }
        else if (t == NT - 3) { asm volatile("s_waitcnt vmcnt(4)" ::: "memory"); }
        else if (t == NT - 2) { asm volatile("s_waitcnt vmcnt(0)" ::: "memory"); }
        __builtin_amdgcn_s_barrier();
        asm volatile("" ::: "memory");
    }
#undef STAGE_A
#undef STAGE_B

    // ---- epilogue: C/D layout col=lane&15, row=quad*4+reg (m89-verified) ----
    float bv[4];
    #pragma unroll
    for (int j = 0; j < 4; ++j) bv[j] = bias[n0 + wn * 64 + j * 16 + l16];

    #pragma unroll
    for (int i = 0; i < 8; ++i) {
        #pragma unroll
        for (int r = 0; r < 4; ++r) {
            int row = m0 + wm * 128 + i * 16 + quad * 4 + r;
            float* cp = C + (size_t)row * GN + (n0 + wn * 64 + l16);
            #pragma unroll
            for (int j = 0; j < 4; ++j)
                cp[j * 16] = acc[i][j][r] + bv[j];
        }
    }
}

// ---------------------------------------------------------------------------
extern "C" void kernel_launch(void* const* d_in, const int* in_sizes, int n_in,
                              void* d_out, int out_size, void* d_ws, size_t ws_size,
                              hipStream_t stream) {
    const float* x = (const float*)d_in[0];  // [4,4096,2048] fp32
    const float* W = (const float*)d_in[1];  // [2048,2048]  fp32
    const float* b = (const float*)d_in[2];  // [2048]       fp32
    float* out = (float*)d_out;              // [4,4096,2048] fp32

    const int d = in_sizes[2];          // 2048
    const int M = in_sizes[0] / d;      // 16384
    const int N = d, K = d;

    // Workspace: A bf16 [M][K] (64 MB) + W' bf16 [N][K] (8 MB)
    unsigned short* A_ws  = (unsigned short*)d_ws;
    unsigned short* Bt_ws = A_ws + (size_t)M * K;

    int n8 = in_sizes[0] / 8;
    cast_x_kernel<<<(n8 + 255) / 256, 256, 0, stream>>>(
        (const float4*)x, (u16x8*)A_ws, n8);

    fwht_w_kernel<<<N, 256, 0, stream>>>(W, Bt_ws);

    dim3 grid(N / 256, M / 256);  // (8, 64) = 512 blocks
    had_gemm_kernel<<<grid, 512, 0, stream>>>(A_ws, Bt_ws, b, out);
}